// Round 8
// baseline (612.816 us; speedup 1.0000x reference)
//
#include <hip/hip_runtime.h>
#include <hip/hip_bf16.h>

typedef __bf16 bf16_t;
typedef bf16_t bf16x8 __attribute__((ext_vector_type(8)));
typedef bf16_t bf16x4 __attribute__((ext_vector_type(4)));
typedef float  f32x4  __attribute__((ext_vector_type(4)));

constexpr int kN = 50000;   // nodes
constexpr int kE = 800000;  // edges
constexpr int kD = 128;     // D == H
constexpr int EPAD = 136;   // bf16 LDS row stride (t1)
constexpr int ASTR = 132;   // aggbuf LDS row stride (fp32)
constexpr int BKT  = 64;    // nodes per bucket == per fused block
constexpr int kCap = 1536;  // per-bucket slot capacity (mean 1024, sd ~32 -> 16 sigma)
constexpr int NBKT = (kN + BKT - 1) / BKT;  // 782
constexpr int PQT  = (kN + 63) / 64;        // 782 P/Q tiles
constexpr int BUCKET_BLOCKS = 512;

__device__ __forceinline__ f32x4 mfma16(bf16x8 a, bf16x8 b, f32x4 c) {
  return __builtin_amdgcn_mfma_f32_16x16x32_bf16(a, b, c, 0, 0, 0);
}
__device__ __forceinline__ float silu_f(float x) {
  return x / (1.0f + __expf(-x));
}

// ---------------- K1: weight transposes + cursor zero ----------------
__global__ void prep_kernel(const float* __restrict__ eW1, const float* __restrict__ eW2,
                            const float* __restrict__ nW1, const float* __restrict__ nW2,
                            bf16_t* __restrict__ W1T, bf16_t* __restrict__ W2T,
                            bf16_t* __restrict__ nW1T, bf16_t* __restrict__ nW2T,
                            int* __restrict__ cursor) {
  const int idx = blockIdx.x * blockDim.x + threadIdx.x;
  const int stride = gridDim.x * blockDim.x;
  for (int i = idx; i < 256 * 128; i += stride) {
    const int n = i >> 8, k = i & 255;  // W1T[n][k] = eW1[k][n]
    W1T[i]  = (bf16_t)eW1[k * 128 + n];
    nW1T[i] = (bf16_t)nW1[k * 128 + n];
  }
  for (int i = idx; i < 128 * 128; i += stride) {
    const int n = i >> 7, k = i & 127;
    W2T[i]  = (bf16_t)eW2[k * 128 + n];
    nW2T[i] = (bf16_t)nW2[k * 128 + n];
  }
  for (int i = idx; i < NBKT * 16; i += stride) cursor[i] = 0;
}

// ---------------- K2: bucket binning (blocks < BUCKET_BLOCKS) + P/Q + h_bf (rest) ----------------
// P = h@eW1_top + eb1, Q = h@eW1_bot. Slot word = (lrow<<16)|col, lrow = row & 63.
__global__ __launch_bounds__(256, 2) void mega_kernel(
    const float* __restrict__ h, const int* __restrict__ ei,
    const bf16_t* __restrict__ W1T, const float* __restrict__ eb1,
    bf16_t* __restrict__ h_bf, bf16_t* __restrict__ P, bf16_t* __restrict__ Q,
    int* __restrict__ cursor, int* __restrict__ slot_lc) {
  __shared__ bf16_t t1[64 * EPAD];

  if (blockIdx.x < BUCKET_BLOCKS) {
    const int idx = blockIdx.x * blockDim.x + threadIdx.x;
    const int stride = BUCKET_BLOCKS * blockDim.x;
    for (int e = idx; e < kE; e += stride) {
      const int r = ei[e];
      const int c = ei[kE + e];
      const int b = r >> 6;
      const int pos = atomicAdd(&cursor[b * 16], 1);
      if (pos < kCap) slot_lc[b * kCap + pos] = ((r & 63) << 16) | c;
    }
    return;
  }

  const int tid  = threadIdx.x;
  const int wv   = tid >> 6;
  const int lane = tid & 63;
  const int l16  = lane & 15;
  const int quad = lane >> 4;
  const int n0 = wv * 32 + l16;
  const int n1 = n0 + 16;
  const float b1v[2] = {eb1[n0], eb1[n1]};
  const int tb = (blockIdx.x - BUCKET_BLOCKS) * 64;

  f32x4 accp[4][2], accq[4][2];
#pragma unroll
  for (int ms = 0; ms < 4; ++ms)
#pragma unroll
    for (int j = 0; j < 2; ++j) {
      accp[ms][j] = (f32x4){0.f, 0.f, 0.f, 0.f};
      accq[ms][j] = (f32x4){0.f, 0.f, 0.f, 0.f};
    }

#pragma unroll
  for (int ks = 0; ks < 4; ++ks) {
    const bf16_t* wp = W1T + ks * 32 + quad * 8;
    const bf16x8 bt0 = *(const bf16x8*)(wp + (size_t)n0 * 256);
    const bf16x8 bt1 = *(const bf16x8*)(wp + (size_t)n1 * 256);
    const bf16x8 bb0 = *(const bf16x8*)(wp + (size_t)n0 * 256 + 128);
    const bf16x8 bb1 = *(const bf16x8*)(wp + (size_t)n1 * 256 + 128);
#pragma unroll
    for (int ms = 0; ms < 4; ++ms) {
      int node = tb + ms * 16 + l16;
      node = node < kN ? node : kN - 1;
      const float* hp = h + (size_t)node * kD + ks * 32 + quad * 8;
      const float4 f0 = *(const float4*)hp;
      const float4 f1 = *(const float4*)(hp + 4);
      const bf16x8 a = {(bf16_t)f0.x, (bf16_t)f0.y, (bf16_t)f0.z, (bf16_t)f0.w,
                        (bf16_t)f1.x, (bf16_t)f1.y, (bf16_t)f1.z, (bf16_t)f1.w};
      *(bf16x8*)(h_bf + (size_t)node * kD + ks * 32 + quad * 8) = a;  // dup-write benign
      accp[ms][0] = mfma16(a, bt0, accp[ms][0]);
      accp[ms][1] = mfma16(a, bt1, accp[ms][1]);
      accq[ms][0] = mfma16(a, bb0, accq[ms][0]);
      accq[ms][1] = mfma16(a, bb1, accq[ms][1]);
    }
  }

#pragma unroll
  for (int ms = 0; ms < 4; ++ms)
#pragma unroll
    for (int j = 0; j < 2; ++j) {
      const int n = wv * 32 + j * 16 + l16;
#pragma unroll
      for (int r = 0; r < 4; ++r)
        t1[(ms * 16 + quad * 4 + r) * EPAD + n] = (bf16_t)(accp[ms][j][r] + b1v[j]);
    }
  __syncthreads();
  {
    const int row = tid >> 2, cc = (tid & 3) * 32;
    const int node = tb + row;
    if (node < kN) {
#pragma unroll
      for (int u = 0; u < 4; ++u)
        *(bf16x8*)(P + (size_t)node * kD + cc + u * 8) = *(const bf16x8*)&t1[row * EPAD + cc + u * 8];
    }
  }
  __syncthreads();
#pragma unroll
  for (int ms = 0; ms < 4; ++ms)
#pragma unroll
    for (int j = 0; j < 2; ++j) {
      const int n = wv * 32 + j * 16 + l16;
#pragma unroll
      for (int r = 0; r < 4; ++r)
        t1[(ms * 16 + quad * 4 + r) * EPAD + n] = (bf16_t)accq[ms][j][r];
    }
  __syncthreads();
  {
    const int row = tid >> 2, cc = (tid & 3) * 32;
    const int node = tb + row;
    if (node < kN) {
#pragma unroll
      for (int u = 0; u < 4; ++u)
        *(bf16x8*)(Q + (size_t)node * kD + cc + u * 8) = *(const bf16x8*)&t1[row * EPAD + cc + u * 8];
    }
  }
}

// ---------------- K3: fused (512 threads = 8 waves per 64-node bucket) ----------------
// LDS counting-sort -> edge MLP (16 edges/wave) -> LDS aggregate -> node MLP. No global atomics.
__global__ __launch_bounds__(512, 6) void fused_kernel(
    const bf16_t* __restrict__ P, const bf16_t* __restrict__ Q,
    const int* __restrict__ slot_lc, const int* __restrict__ cursor,
    const bf16_t* __restrict__ W2T, const float* __restrict__ eb2,
    const bf16_t* __restrict__ h_bf, const float* __restrict__ h,
    const bf16_t* __restrict__ nW1T, const bf16_t* __restrict__ nW2T,
    const float* __restrict__ nb1, const float* __restrict__ nb2,
    float* __restrict__ out) {
  __shared__ float aggbuf[BKT * ASTR];  // 33792 B; aliased by t1 (17408 B) in node phase
  __shared__ int  sorted[kCap];         // 6144 B: bucket slots, row-grouped
  __shared__ int  s_bin[BKT];           // hist -> cursor

  const int tid  = threadIdx.x;
  const int wv   = tid >> 6;            // 0..7
  const int lane = tid & 63;
  const int l16  = lane & 15;
  const int quad = lane >> 4;
  const int g0   = blockIdx.x * BKT;

  for (int i = tid; i < BKT * ASTR; i += 512) aggbuf[i] = 0.0f;
  if (tid < BKT) s_bin[tid] = 0;
  const int cnt = min(cursor[blockIdx.x * 16], kCap);
  const int sbase = blockIdx.x * kCap;
  __syncthreads();

  // ---- counting sort by lrow (order within row irrelevant) ----
  for (int i = tid; i < cnt; i += 512) atomicAdd(&s_bin[slot_lc[sbase + i] >> 16], 1);
  __syncthreads();
  if (tid == 0) {
    int run = 0;
#pragma unroll
    for (int r = 0; r < BKT; ++r) {
      const int c = s_bin[r];
      s_bin[r] = run;
      run += c;
    }
  }
  __syncthreads();
  for (int i = tid; i < cnt; i += 512) {
    const int w = slot_lc[sbase + i];
    sorted[atomicAdd(&s_bin[w >> 16], 1)] = w;
  }
  __syncthreads();

  float b2v[8];
#pragma unroll
  for (int j = 0; j < 8; ++j) b2v[j] = eb2[j * 16 + l16];

  // ---- edge phase: 128-edge tiles, 16 edges per wave ----
  const int ntiles = (cnt + 127) >> 7;
  for (int t = 0; t < ntiles; ++t) {
    const int idx = t * 128 + wv * 16 + l16;
    const int w = (idx < cnt) ? sorted[idx] : -1;
    const int lr = (w >= 0) ? (w >> 16) : -1;
    const int cn = (w >= 0) ? (w & 0xFFFF) : 0;
    const int pr = (w >= 0) ? (g0 + lr) : g0;

    bf16x8 af[4];
#pragma unroll
    for (int ks = 0; ks < 4; ++ks) {
      const bf16x8 p = *(const bf16x8*)(P + (size_t)pr * kD + ks * 32 + quad * 8);
      const bf16x8 q = *(const bf16x8*)(Q + (size_t)cn * kD + ks * 32 + quad * 8);
      bf16x8 a;
#pragma unroll
      for (int u = 0; u < 8; ++u) a[u] = (bf16_t)silu_f((float)p[u] + (float)q[u]);
      af[ks] = a;
    }

    f32x4 acc[8];
#pragma unroll
    for (int j = 0; j < 8; ++j) acc[j] = (f32x4){0.f, 0.f, 0.f, 0.f};

#pragma unroll
    for (int ks = 0; ks < 4; ++ks)
#pragma unroll
      for (int j = 0; j < 8; ++j) {
        const bf16x8 b = *(const bf16x8*)(W2T + (size_t)(j * 16 + l16) * kD + ks * 32 + quad * 8);
        acc[j] = mfma16(af[ks], b, acc[j]);
      }

    // epilogue: silu + run-merged LDS atomic scatter (rows grouped by sort)
    int rows[4];
#pragma unroll
    for (int r = 0; r < 4; ++r) rows[r] = __shfl(lr, quad * 4 + r, 64);
#pragma unroll
    for (int j = 0; j < 8; ++j) {
      const int cbase = j * 16 + l16;
      float run = silu_f(acc[j][0] + b2v[j]);
      int cur = rows[0];
#pragma unroll
      for (int r = 1; r < 4; ++r) {
        const float v = silu_f(acc[j][r] + b2v[j]);
        if (rows[r] == cur) {
          run += v;
        } else {
          if (cur >= 0) atomicAdd(&aggbuf[cur * ASTR + cbase], run);
          cur = rows[r];
          run = v;
        }
      }
      if (cur >= 0) atomicAdd(&aggbuf[cur * ASTR + cbase], run);
    }
  }
  __syncthreads();

  // ---- node phase: out = h + silu([h | agg] @ nW1 + nb1) @ nW2 + nb2 ----
  // 8 waves: wr = node-half (32 nodes), wc = col-slice (32 cols)
  const int wr = wv >> 2;
  const int wc = wv & 3;
  const int n0 = wc * 32 + l16;
  const int n1 = n0 + 16;
  const float b1v[2] = {nb1[n0], nb1[n1]};
  const float b2n[2] = {nb2[n0], nb2[n1]};

  f32x4 acc[2][2];
#pragma unroll
  for (int ms = 0; ms < 2; ++ms)
#pragma unroll
    for (int j = 0; j < 2; ++j) acc[ms][j] = (f32x4){0.f, 0.f, 0.f, 0.f};

#pragma unroll
  for (int ks = 0; ks < 8; ++ks) {
    const bf16_t* wp = nW1T + ks * 32 + quad * 8;
    const bf16x8 b0 = *(const bf16x8*)(wp + (size_t)n0 * 256);
    const bf16x8 bq = *(const bf16x8*)(wp + (size_t)n1 * 256);
#pragma unroll
    for (int ms = 0; ms < 2; ++ms) {
      const int m = wr * 32 + ms * 16 + l16;
      bf16x8 a;
      if (ks < 4) {
        int node = g0 + m;
        node = node < kN ? node : kN - 1;
        a = *(const bf16x8*)(h_bf + (size_t)node * kD + ks * 32 + quad * 8);
      } else {
        const float* ap = &aggbuf[m * ASTR + (ks - 4) * 32 + quad * 8];
        const float4 f0 = *(const float4*)ap;
        const float4 f1 = *(const float4*)(ap + 4);
        a = (bf16x8){(bf16_t)f0.x, (bf16_t)f0.y, (bf16_t)f0.z, (bf16_t)f0.w,
                     (bf16_t)f1.x, (bf16_t)f1.y, (bf16_t)f1.z, (bf16_t)f1.w};
      }
      acc[ms][0] = mfma16(a, b0, acc[ms][0]);
      acc[ms][1] = mfma16(a, bq, acc[ms][1]);
    }
  }
  __syncthreads();  // aggbuf reads done -> alias t1

  bf16_t* t1 = (bf16_t*)aggbuf;
#pragma unroll
  for (int ms = 0; ms < 2; ++ms)
#pragma unroll
    for (int j = 0; j < 2; ++j) {
      const int n = wc * 32 + j * 16 + l16;
#pragma unroll
      for (int r = 0; r < 4; ++r) {
        const int m = wr * 32 + ms * 16 + quad * 4 + r;
        t1[m * EPAD + n] = (bf16_t)silu_f(acc[ms][j][r] + b1v[j]);
      }
    }
  __syncthreads();

  f32x4 acc2[2][2];
#pragma unroll
  for (int ms = 0; ms < 2; ++ms)
#pragma unroll
    for (int j = 0; j < 2; ++j) acc2[ms][j] = (f32x4){0.f, 0.f, 0.f, 0.f};
#pragma unroll
  for (int ks = 0; ks < 4; ++ks) {
    const bf16_t* wp = nW2T + ks * 32 + quad * 8;
    const bf16x8 b0 = *(const bf16x8*)(wp + (size_t)n0 * 128);
    const bf16x8 bq = *(const bf16x8*)(wp + (size_t)n1 * 128);
#pragma unroll
    for (int ms = 0; ms < 2; ++ms) {
      const bf16x8 a = *(const bf16x8*)&t1[(wr * 32 + ms * 16 + l16) * EPAD + ks * 32 + quad * 8];
      acc2[ms][0] = mfma16(a, b0, acc2[ms][0]);
      acc2[ms][1] = mfma16(a, bq, acc2[ms][1]);
    }
  }

#pragma unroll
  for (int ms = 0; ms < 2; ++ms)
#pragma unroll
    for (int j = 0; j < 2; ++j) {
      const int n = wc * 32 + j * 16 + l16;
#pragma unroll
      for (int r = 0; r < 4; ++r) {
        const int node = g0 + wr * 32 + ms * 16 + quad * 4 + r;
        if (node < kN) {
          const size_t o = (size_t)node * kD + n;
          out[o] = h[o] + acc2[ms][j][r] + b2n[j];
        }
      }
    }
}

// ---------------- launch ----------------
extern "C" void kernel_launch(void* const* d_in, const int* in_sizes, int n_in,
                              void* d_out, int out_size, void* d_ws, size_t ws_size,
                              hipStream_t stream) {
  const float* h   = (const float*)d_in[0];
  const int*   ei  = (const int*)d_in[1];
  const float* eW1 = (const float*)d_in[2];
  const float* eb1 = (const float*)d_in[3];
  const float* eW2 = (const float*)d_in[4];
  const float* eb2 = (const float*)d_in[5];
  const float* nW1 = (const float*)d_in[6];
  const float* nb1 = (const float*)d_in[7];
  const float* nW2 = (const float*)d_in[8];
  const float* nb2 = (const float*)d_in[9];
  float* out = (float*)d_out;

  char* ws = (char*)d_ws;
  size_t off = 0;
  auto alloc = [&](size_t bytes) {
    void* p = ws + off;
    off += (bytes + 255) & ~(size_t)255;
    return p;
  };
  bf16_t* h_bf    = (bf16_t*)alloc((size_t)kN * kD * 2);   // 12.8 MB
  bf16_t* W1T     = (bf16_t*)alloc(256 * 128 * 2);
  bf16_t* W2T     = (bf16_t*)alloc(128 * 128 * 2);
  bf16_t* nW1T    = (bf16_t*)alloc(256 * 128 * 2);
  bf16_t* nW2T    = (bf16_t*)alloc(128 * 128 * 2);
  bf16_t* P       = (bf16_t*)alloc((size_t)kN * kD * 2);   // 12.8 MB
  bf16_t* Q       = (bf16_t*)alloc((size_t)kN * kD * 2);   // 12.8 MB
  int*    cursor  = (int*)alloc((size_t)NBKT * 16 * 4);    // 50 KB, 64 B padded
  int*    slot_lc = (int*)alloc((size_t)NBKT * kCap * 4);  // 4.8 MB

  prep_kernel<<<128, 256, 0, stream>>>(eW1, eW2, nW1, nW2, W1T, W2T, nW1T, nW2T, cursor);
  mega_kernel<<<BUCKET_BLOCKS + PQT, 256, 0, stream>>>(h, ei, W1T, eb1,
                                                       h_bf, P, Q, cursor, slot_lc);
  fused_kernel<<<NBKT, 512, 0, stream>>>(P, Q, slot_lc, cursor, W2T, eb2,
                                         h_bf, h, nW1T, nW2T, nb1, nb2, out);
}

// Round 9
// 429.006 us; speedup vs baseline: 1.4285x; 1.4285x over previous
//
#include <hip/hip_runtime.h>
#include <hip/hip_bf16.h>

typedef __bf16 bf16_t;
typedef bf16_t bf16x8 __attribute__((ext_vector_type(8)));
typedef float  f32x4  __attribute__((ext_vector_type(4)));

constexpr int kN = 50000;   // nodes
constexpr int kE = 800000;  // edges
constexpr int kD = 128;     // D == H
constexpr int EPAD = 136;   // bf16 LDS row stride
constexpr int ASTR = 132;   // aggbuf LDS row stride (fp32)
constexpr int BKT  = 32;    // nodes per bucket == per fused block
constexpr int kCap = 1024;  // per-bucket slot capacity (mean 512)
constexpr int NBKT = (kN + BKT - 1) / BKT;  // 1563
constexpr int PQT  = (kN + 63) / 64;        // 782 P/Q tiles
constexpr int BUCKET_BLOCKS = 512;

__device__ __forceinline__ f32x4 mfma16(bf16x8 a, bf16x8 b, f32x4 c) {
  return __builtin_amdgcn_mfma_f32_16x16x32_bf16(a, b, c, 0, 0, 0);
}
__device__ __forceinline__ float silu_f(float x) {
  return x / (1.0f + __expf(-x));
}

// ---------------- K1: weight transposes + cursor zero ----------------
__global__ void prep_kernel(const float* __restrict__ eW1, const float* __restrict__ eW2,
                            const float* __restrict__ nW1, const float* __restrict__ nW2,
                            bf16_t* __restrict__ W1T, bf16_t* __restrict__ W2T,
                            bf16_t* __restrict__ nW1T, bf16_t* __restrict__ nW2T,
                            int* __restrict__ cursor) {
  const int idx = blockIdx.x * blockDim.x + threadIdx.x;
  const int stride = gridDim.x * blockDim.x;
  for (int i = idx; i < 256 * 128; i += stride) {
    const int n = i >> 8, k = i & 255;  // W1T[n][k] = eW1[k][n]
    W1T[i]  = (bf16_t)eW1[k * 128 + n];
    nW1T[i] = (bf16_t)nW1[k * 128 + n];
  }
  for (int i = idx; i < 128 * 128; i += stride) {
    const int n = i >> 7, k = i & 127;
    W2T[i]  = (bf16_t)eW2[k * 128 + n];
    nW2T[i] = (bf16_t)nW2[k * 128 + n];
  }
  for (int i = idx; i < NBKT * 16; i += stride) cursor[i] = 0;
}

// ---------------- K2: bucket binning (blocks < BUCKET_BLOCKS) + P/Q + h_bf (rest) ----------------
// P = h@eW1_top + eb1, Q = h@eW1_bot. Slot word = (lrow<<16)|col, lrow = row & 31.
__global__ __launch_bounds__(256, 2) void mega_kernel(
    const float* __restrict__ h, const int* __restrict__ ei,
    const bf16_t* __restrict__ W1T, const float* __restrict__ eb1,
    bf16_t* __restrict__ h_bf, bf16_t* __restrict__ P, bf16_t* __restrict__ Q,
    int* __restrict__ cursor, int* __restrict__ slot_lc) {
  __shared__ bf16_t t1[64 * EPAD];

  if (blockIdx.x < BUCKET_BLOCKS) {
    const int idx = blockIdx.x * blockDim.x + threadIdx.x;
    const int stride = BUCKET_BLOCKS * blockDim.x;
    for (int e = idx; e < kE; e += stride) {
      const int r = ei[e];
      const int c = ei[kE + e];
      const int b = r >> 5;
      const int pos = atomicAdd(&cursor[b * 16], 1);
      if (pos < kCap) slot_lc[b * kCap + pos] = ((r & 31) << 16) | c;
    }
    return;
  }

  const int tid  = threadIdx.x;
  const int wv   = tid >> 6;
  const int lane = tid & 63;
  const int l16  = lane & 15;
  const int quad = lane >> 4;
  const int n0 = wv * 32 + l16;
  const int n1 = n0 + 16;
  const float b1v[2] = {eb1[n0], eb1[n1]};
  const int tb = (blockIdx.x - BUCKET_BLOCKS) * 64;

  f32x4 accp[4][2], accq[4][2];
#pragma unroll
  for (int ms = 0; ms < 4; ++ms)
#pragma unroll
    for (int j = 0; j < 2; ++j) {
      accp[ms][j] = (f32x4){0.f, 0.f, 0.f, 0.f};
      accq[ms][j] = (f32x4){0.f, 0.f, 0.f, 0.f};
    }

#pragma unroll
  for (int ks = 0; ks < 4; ++ks) {
    const bf16_t* wp = W1T + ks * 32 + quad * 8;
    const bf16x8 bt0 = *(const bf16x8*)(wp + (size_t)n0 * 256);
    const bf16x8 bt1 = *(const bf16x8*)(wp + (size_t)n1 * 256);
    const bf16x8 bb0 = *(const bf16x8*)(wp + (size_t)n0 * 256 + 128);
    const bf16x8 bb1 = *(const bf16x8*)(wp + (size_t)n1 * 256 + 128);
#pragma unroll
    for (int ms = 0; ms < 4; ++ms) {
      int node = tb + ms * 16 + l16;
      node = node < kN ? node : kN - 1;
      const float* hp = h + (size_t)node * kD + ks * 32 + quad * 8;
      const float4 f0 = *(const float4*)hp;
      const float4 f1 = *(const float4*)(hp + 4);
      const bf16x8 a = {(bf16_t)f0.x, (bf16_t)f0.y, (bf16_t)f0.z, (bf16_t)f0.w,
                        (bf16_t)f1.x, (bf16_t)f1.y, (bf16_t)f1.z, (bf16_t)f1.w};
      *(bf16x8*)(h_bf + (size_t)node * kD + ks * 32 + quad * 8) = a;  // dup-write benign
      accp[ms][0] = mfma16(a, bt0, accp[ms][0]);
      accp[ms][1] = mfma16(a, bt1, accp[ms][1]);
      accq[ms][0] = mfma16(a, bb0, accq[ms][0]);
      accq[ms][1] = mfma16(a, bb1, accq[ms][1]);
    }
  }

#pragma unroll
  for (int ms = 0; ms < 4; ++ms)
#pragma unroll
    for (int j = 0; j < 2; ++j) {
      const int n = wv * 32 + j * 16 + l16;
#pragma unroll
      for (int r = 0; r < 4; ++r)
        t1[(ms * 16 + quad * 4 + r) * EPAD + n] = (bf16_t)(accp[ms][j][r] + b1v[j]);
    }
  __syncthreads();
  {
    const int row = tid >> 2, cc = (tid & 3) * 32;
    const int node = tb + row;
    if (node < kN) {
#pragma unroll
      for (int u = 0; u < 4; ++u)
        *(bf16x8*)(P + (size_t)node * kD + cc + u * 8) = *(const bf16x8*)&t1[row * EPAD + cc + u * 8];
    }
  }
  __syncthreads();
#pragma unroll
  for (int ms = 0; ms < 4; ++ms)
#pragma unroll
    for (int j = 0; j < 2; ++j) {
      const int n = wv * 32 + j * 16 + l16;
#pragma unroll
      for (int r = 0; r < 4; ++r)
        t1[(ms * 16 + quad * 4 + r) * EPAD + n] = (bf16_t)accq[ms][j][r];
    }
  __syncthreads();
  {
    const int row = tid >> 2, cc = (tid & 3) * 32;
    const int node = tb + row;
    if (node < kN) {
#pragma unroll
      for (int u = 0; u < 4; ++u)
        *(bf16x8*)(Q + (size_t)node * kD + cc + u * 8) = *(const bf16x8*)&t1[row * EPAD + cc + u * 8];
    }
  }
}

// ---------------- K3: fused: sort -> edge MLP (Q via LDS-DMA dbuf) -> LDS agg -> node MLP ----------------
// Block b owns nodes [b*32, b*32+32) and slot bucket b. Each wave consumes only the Q bytes
// it DMA'd itself -> no barrier in the edge loop, overlap via vmcnt(4).
__global__ __launch_bounds__(256, 2) void fused_kernel(
    const bf16_t* __restrict__ P, const bf16_t* __restrict__ Q,
    const int* __restrict__ slot_lc, const int* __restrict__ cursor,
    const bf16_t* __restrict__ W2T, const float* __restrict__ eb2,
    const bf16_t* __restrict__ h_bf, const float* __restrict__ h,
    const bf16_t* __restrict__ nW1T, const bf16_t* __restrict__ nW2T,
    const float* __restrict__ nb1, const float* __restrict__ nb2,
    float* __restrict__ out) {
  __shared__ float aggbuf[BKT * ASTR];    // 16896 B; aliased by t1 in node phase
  __shared__ int  sorted[kCap];           // 4096 B
  __shared__ int  s_bin[BKT];             // 128 B
  __shared__ bf16_t P_lds[BKT * EPAD];    // 8704 B
  __shared__ bf16_t qbuf[2 * 64 * kD];    // 32768 B: 2 bufs x 64 edges x 256 B

  const int tid  = threadIdx.x;
  const int wv   = tid >> 6;              // 0..3
  const int lane = tid & 63;
  const int l16  = lane & 15;
  const int quad = lane >> 4;
  const int g0   = blockIdx.x * BKT;

  for (int i = tid; i < BKT * ASTR; i += 256) aggbuf[i] = 0.0f;
  if (tid < BKT) s_bin[tid] = 0;
  // stage this block's 32 P rows (read once)
  for (int i = tid; i < BKT * 16; i += 256) {
    const int row = i >> 4, fo = (i & 15) * 8;
    const int gr = min(g0 + row, kN - 1);
    *(bf16x8*)&P_lds[row * EPAD + fo] = *(const bf16x8*)(P + (size_t)gr * kD + fo);
  }
  const int cnt = min(cursor[blockIdx.x * 16], kCap);
  const int sbase = blockIdx.x * kCap;
  __syncthreads();

  // ---- counting sort by lrow ----
  for (int i = tid; i < cnt; i += 256) atomicAdd(&s_bin[slot_lc[sbase + i] >> 16], 1);
  __syncthreads();
  if (tid == 0) {
    int run = 0;
#pragma unroll
    for (int r = 0; r < BKT; ++r) {
      const int c = s_bin[r];
      s_bin[r] = run;
      run += c;
    }
  }
  __syncthreads();
  for (int i = tid; i < cnt; i += 256) {
    const int w = slot_lc[sbase + i];
    sorted[atomicAdd(&s_bin[w >> 16], 1)] = w;
  }
  __syncthreads();

  float b2v[8];
#pragma unroll
  for (int j = 0; j < 8; ++j) b2v[j] = eb2[j * 16 + l16];

  // ---- edge phase: 64-edge tiles (16/wave), Q double-buffered via global_load_lds ----
  // DMA lane map: lane l -> edge e=l&15, chunk q=l>>4; instr i covers byte chunk (i*4+q)*16
  // of Q row. LDS layout: buf*16384 + wv*4096 + i*1024 + l*16  => [ks=i][quad=q][e]*16B.
  const int ntiles = (cnt + 63) >> 6;
  char* qb_bytes = (char*)qbuf;

  auto dma_tile = [&](int buf, int col) {
    const char* gp = (const char*)(Q + (size_t)col * kD) + quad * 16;
    char* lb = qb_bytes + buf * 16384 + wv * 4096;
#pragma unroll
    for (int i = 0; i < 4; ++i) {
      __builtin_amdgcn_global_load_lds(
          (const __attribute__((address_space(1))) void*)(gp + i * 64),
          (__attribute__((address_space(3))) void*)(lb + i * 1024),
          16, 0, 0);
    }
  };

  int w_cur = -1;
  if (ntiles > 0) {
    const int idx0 = wv * 16 + l16;
    w_cur = (idx0 < cnt) ? sorted[idx0] : -1;
    dma_tile(0, (w_cur >= 0) ? (w_cur & 0xFFFF) : 0);
  }

  for (int t = 0; t < ntiles; ++t) {
    const int idxn = (t + 1) * 64 + wv * 16 + l16;
    const int w_nxt = (idxn < cnt) ? sorted[idxn] : -1;
    dma_tile((t + 1) & 1, (w_nxt >= 0) ? (w_nxt & 0xFFFF) : 0);  // always issue: keeps vmcnt math uniform
    __builtin_amdgcn_s_waitcnt(0x0F74);   // vmcnt(4): tile t's 4 DMAs complete
    __builtin_amdgcn_sched_barrier(0);    // keep ds_reads below the wait

    const int lr = (w_cur >= 0) ? (w_cur >> 16) : -1;
    const int lrow = (lr >= 0) ? lr : 0;
    const bf16_t* qb = qbuf + (size_t)((t & 1) * 8192 + wv * 2048 + quad * 128 + l16 * 8);

    bf16x8 af[4];
#pragma unroll
    for (int ks = 0; ks < 4; ++ks) {
      const bf16x8 p = *(const bf16x8*)&P_lds[lrow * EPAD + ks * 32 + quad * 8];
      const bf16x8 q = *(const bf16x8*)(qb + ks * 512);
      bf16x8 a;
#pragma unroll
      for (int u = 0; u < 8; ++u) a[u] = (bf16_t)silu_f((float)p[u] + (float)q[u]);
      af[ks] = a;
    }

    f32x4 acc[8];
#pragma unroll
    for (int j = 0; j < 8; ++j) acc[j] = (f32x4){0.f, 0.f, 0.f, 0.f};
#pragma unroll
    for (int ks = 0; ks < 4; ++ks)
#pragma unroll
      for (int j = 0; j < 8; ++j) {
        const bf16x8 b = *(const bf16x8*)(W2T + (size_t)(j * 16 + l16) * kD + ks * 32 + quad * 8);
        acc[j] = mfma16(af[ks], b, acc[j]);
      }

    // epilogue: silu + run-merged LDS atomic scatter (rows grouped by sort)
    int rows[4];
#pragma unroll
    for (int r = 0; r < 4; ++r) rows[r] = __shfl(lr, quad * 4 + r, 64);
#pragma unroll
    for (int j = 0; j < 8; ++j) {
      const int cbase = j * 16 + l16;
      float run = silu_f(acc[j][0] + b2v[j]);
      int cur = rows[0];
#pragma unroll
      for (int r = 1; r < 4; ++r) {
        const float v = silu_f(acc[j][r] + b2v[j]);
        if (rows[r] == cur) {
          run += v;
        } else {
          if (cur >= 0) atomicAdd(&aggbuf[cur * ASTR + cbase], run);
          cur = rows[r];
          run = v;
        }
      }
      if (cur >= 0) atomicAdd(&aggbuf[cur * ASTR + cbase], run);
    }
    w_cur = w_nxt;
  }
  __syncthreads();

  // ---- node phase: out = h + silu([h | agg] @ nW1 + nb1) @ nW2 + nb2 ----
  const int n0 = wv * 32 + l16;
  const int n1 = n0 + 16;
  const float b1v[2] = {nb1[n0], nb1[n1]};
  const float b2n[2] = {nb2[n0], nb2[n1]};

  f32x4 acc[2][2];
#pragma unroll
  for (int ms = 0; ms < 2; ++ms)
#pragma unroll
    for (int j = 0; j < 2; ++j) acc[ms][j] = (f32x4){0.f, 0.f, 0.f, 0.f};

#pragma unroll
  for (int ks = 0; ks < 8; ++ks) {
    const bf16_t* wp = nW1T + ks * 32 + quad * 8;
    const bf16x8 b0 = *(const bf16x8*)(wp + (size_t)n0 * 256);
    const bf16x8 bq = *(const bf16x8*)(wp + (size_t)n1 * 256);
#pragma unroll
    for (int ms = 0; ms < 2; ++ms) {
      bf16x8 a;
      if (ks < 4) {
        int node = g0 + ms * 16 + l16;
        node = node < kN ? node : kN - 1;
        a = *(const bf16x8*)(h_bf + (size_t)node * kD + ks * 32 + quad * 8);
      } else {
        const int lrow = ms * 16 + l16;
        const float* ap = &aggbuf[lrow * ASTR + (ks - 4) * 32 + quad * 8];
        const float4 f0 = *(const float4*)ap;
        const float4 f1 = *(const float4*)(ap + 4);
        a = (bf16x8){(bf16_t)f0.x, (bf16_t)f0.y, (bf16_t)f0.z, (bf16_t)f0.w,
                     (bf16_t)f1.x, (bf16_t)f1.y, (bf16_t)f1.z, (bf16_t)f1.w};
      }
      acc[ms][0] = mfma16(a, b0, acc[ms][0]);
      acc[ms][1] = mfma16(a, bq, acc[ms][1]);
    }
  }
  __syncthreads();  // aggbuf reads done -> alias t1

  bf16_t* t1 = (bf16_t*)aggbuf;
#pragma unroll
  for (int ms = 0; ms < 2; ++ms)
#pragma unroll
    for (int j = 0; j < 2; ++j) {
      const int n = wv * 32 + j * 16 + l16;
#pragma unroll
      for (int r = 0; r < 4; ++r) {
        const int m = ms * 16 + quad * 4 + r;
        t1[m * EPAD + n] = (bf16_t)silu_f(acc[ms][j][r] + b1v[j]);
      }
    }
  __syncthreads();

  f32x4 acc2[2][2];
#pragma unroll
  for (int ms = 0; ms < 2; ++ms)
#pragma unroll
    for (int j = 0; j < 2; ++j) acc2[ms][j] = (f32x4){0.f, 0.f, 0.f, 0.f};
#pragma unroll
  for (int ks = 0; ks < 4; ++ks) {
    const bf16_t* wp = nW2T + ks * 32 + quad * 8;
    const bf16x8 b0 = *(const bf16x8*)(wp + (size_t)n0 * 128);
    const bf16x8 bq = *(const bf16x8*)(wp + (size_t)n1 * 128);
#pragma unroll
    for (int ms = 0; ms < 2; ++ms) {
      const bf16x8 a = *(const bf16x8*)&t1[(ms * 16 + l16) * EPAD + ks * 32 + quad * 8];
      acc2[ms][0] = mfma16(a, b0, acc2[ms][0]);
      acc2[ms][1] = mfma16(a, bq, acc2[ms][1]);
    }
  }

#pragma unroll
  for (int ms = 0; ms < 2; ++ms)
#pragma unroll
    for (int j = 0; j < 2; ++j) {
      const int n = wv * 32 + j * 16 + l16;
#pragma unroll
      for (int r = 0; r < 4; ++r) {
        const int node = g0 + ms * 16 + quad * 4 + r;
        if (node < kN) {
          const size_t o = (size_t)node * kD + n;
          out[o] = h[o] + acc2[ms][j][r] + b2n[j];
        }
      }
    }
}

// ---------------- launch ----------------
extern "C" void kernel_launch(void* const* d_in, const int* in_sizes, int n_in,
                              void* d_out, int out_size, void* d_ws, size_t ws_size,
                              hipStream_t stream) {
  const float* h   = (const float*)d_in[0];
  const int*   ei  = (const int*)d_in[1];
  const float* eW1 = (const float*)d_in[2];
  const float* eb1 = (const float*)d_in[3];
  const float* eW2 = (const float*)d_in[4];
  const float* eb2 = (const float*)d_in[5];
  const float* nW1 = (const float*)d_in[6];
  const float* nb1 = (const float*)d_in[7];
  const float* nW2 = (const float*)d_in[8];
  const float* nb2 = (const float*)d_in[9];
  float* out = (float*)d_out;

  char* ws = (char*)d_ws;
  size_t off = 0;
  auto alloc = [&](size_t bytes) {
    void* p = ws + off;
    off += (bytes + 255) & ~(size_t)255;
    return p;
  };
  bf16_t* h_bf    = (bf16_t*)alloc((size_t)kN * kD * 2);   // 12.8 MB
  bf16_t* W1T     = (bf16_t*)alloc(256 * 128 * 2);
  bf16_t* W2T     = (bf16_t*)alloc(128 * 128 * 2);
  bf16_t* nW1T    = (bf16_t*)alloc(256 * 128 * 2);
  bf16_t* nW2T    = (bf16_t*)alloc(128 * 128 * 2);
  bf16_t* P       = (bf16_t*)alloc((size_t)kN * kD * 2);   // 12.8 MB
  bf16_t* Q       = (bf16_t*)alloc((size_t)kN * kD * 2);   // 12.8 MB
  int*    cursor  = (int*)alloc((size_t)NBKT * 16 * 4);    // 100 KB, 64 B padded
  int*    slot_lc = (int*)alloc((size_t)NBKT * kCap * 4);  // 6.4 MB

  prep_kernel<<<128, 256, 0, stream>>>(eW1, eW2, nW1, nW2, W1T, W2T, nW1T, nW2T, cursor);
  mega_kernel<<<BUCKET_BLOCKS + PQT, 256, 0, stream>>>(h, ei, W1T, eb1,
                                                       h_bf, P, Q, cursor, slot_lc);
  fused_kernel<<<NBKT, 256, 0, stream>>>(P, Q, slot_lc, cursor, W2T, eb2,
                                         h_bf, h, nW1T, nW2T, nb1, nb2, out);
}

// Round 10
// 421.690 us; speedup vs baseline: 1.4532x; 1.0173x over previous
//
#include <hip/hip_runtime.h>
#include <hip/hip_bf16.h>

typedef __bf16 bf16_t;
typedef bf16_t bf16x8 __attribute__((ext_vector_type(8)));
typedef float  f32x4  __attribute__((ext_vector_type(4)));

constexpr int kN = 50000;   // nodes
constexpr int kE = 800000;  // edges
constexpr int kD = 128;     // D == H
constexpr int EPAD = 136;   // bf16 LDS row stride
constexpr int ASTR = 132;   // aggbuf LDS row stride (fp32)
constexpr int BKT  = 32;    // nodes per bucket == per fused block
constexpr int kCap = 1024;  // per-bucket slot capacity (mean 512)
constexpr int NBKT = (kN + BKT - 1) / BKT;  // 1563
constexpr int PQT  = (kN + 63) / 64;        // 782 P/Q tiles
constexpr int BUCKET_BLOCKS = 512;

__device__ __forceinline__ f32x4 mfma16(bf16x8 a, bf16x8 b, f32x4 c) {
  return __builtin_amdgcn_mfma_f32_16x16x32_bf16(a, b, c, 0, 0, 0);
}
__device__ __forceinline__ float silu_f(float x) {
  return x / (1.0f + __expf(-x));
}

// ---------------- K1: weight transposes + cursor zero ----------------
__global__ void prep_kernel(const float* __restrict__ eW1, const float* __restrict__ eW2,
                            const float* __restrict__ nW1, const float* __restrict__ nW2,
                            bf16_t* __restrict__ W1T, bf16_t* __restrict__ W2T,
                            bf16_t* __restrict__ nW1T, bf16_t* __restrict__ nW2T,
                            int* __restrict__ cursor) {
  const int idx = blockIdx.x * blockDim.x + threadIdx.x;
  const int stride = gridDim.x * blockDim.x;
  for (int i = idx; i < 256 * 128; i += stride) {
    const int n = i >> 8, k = i & 255;  // W1T[n][k] = eW1[k][n]
    W1T[i]  = (bf16_t)eW1[k * 128 + n];
    nW1T[i] = (bf16_t)nW1[k * 128 + n];
  }
  for (int i = idx; i < 128 * 128; i += stride) {
    const int n = i >> 7, k = i & 127;
    W2T[i]  = (bf16_t)eW2[k * 128 + n];
    nW2T[i] = (bf16_t)nW2[k * 128 + n];
  }
  for (int i = idx; i < NBKT * 16; i += stride) cursor[i] = 0;
}

// ---------------- K2: bucket binning (blocks < BUCKET_BLOCKS) + P/Q + h_bf (rest) ----------------
// P = h@eW1_top + eb1, Q = h@eW1_bot. Slot word = (lrow<<16)|col, lrow = row & 31.
__global__ __launch_bounds__(256, 2) void mega_kernel(
    const float* __restrict__ h, const int* __restrict__ ei,
    const bf16_t* __restrict__ W1T, const float* __restrict__ eb1,
    bf16_t* __restrict__ h_bf, bf16_t* __restrict__ P, bf16_t* __restrict__ Q,
    int* __restrict__ cursor, int* __restrict__ slot_lc) {
  __shared__ bf16_t t1[64 * EPAD];

  if (blockIdx.x < BUCKET_BLOCKS) {
    const int idx = blockIdx.x * blockDim.x + threadIdx.x;
    const int stride = BUCKET_BLOCKS * blockDim.x;
    for (int e = idx; e < kE; e += stride) {
      const int r = ei[e];
      const int c = ei[kE + e];
      const int b = r >> 5;
      const int pos = atomicAdd(&cursor[b * 16], 1);
      if (pos < kCap) slot_lc[b * kCap + pos] = ((r & 31) << 16) | c;
    }
    return;
  }

  const int tid  = threadIdx.x;
  const int wv   = tid >> 6;
  const int lane = tid & 63;
  const int l16  = lane & 15;
  const int quad = lane >> 4;
  const int n0 = wv * 32 + l16;
  const int n1 = n0 + 16;
  const float b1v[2] = {eb1[n0], eb1[n1]};
  const int tb = (blockIdx.x - BUCKET_BLOCKS) * 64;

  f32x4 accp[4][2], accq[4][2];
#pragma unroll
  for (int ms = 0; ms < 4; ++ms)
#pragma unroll
    for (int j = 0; j < 2; ++j) {
      accp[ms][j] = (f32x4){0.f, 0.f, 0.f, 0.f};
      accq[ms][j] = (f32x4){0.f, 0.f, 0.f, 0.f};
    }

#pragma unroll
  for (int ks = 0; ks < 4; ++ks) {
    const bf16_t* wp = W1T + ks * 32 + quad * 8;
    const bf16x8 bt0 = *(const bf16x8*)(wp + (size_t)n0 * 256);
    const bf16x8 bt1 = *(const bf16x8*)(wp + (size_t)n1 * 256);
    const bf16x8 bb0 = *(const bf16x8*)(wp + (size_t)n0 * 256 + 128);
    const bf16x8 bb1 = *(const bf16x8*)(wp + (size_t)n1 * 256 + 128);
#pragma unroll
    for (int ms = 0; ms < 4; ++ms) {
      int node = tb + ms * 16 + l16;
      node = node < kN ? node : kN - 1;
      const float* hp = h + (size_t)node * kD + ks * 32 + quad * 8;
      const float4 f0 = *(const float4*)hp;
      const float4 f1 = *(const float4*)(hp + 4);
      const bf16x8 a = {(bf16_t)f0.x, (bf16_t)f0.y, (bf16_t)f0.z, (bf16_t)f0.w,
                        (bf16_t)f1.x, (bf16_t)f1.y, (bf16_t)f1.z, (bf16_t)f1.w};
      *(bf16x8*)(h_bf + (size_t)node * kD + ks * 32 + quad * 8) = a;  // dup-write benign
      accp[ms][0] = mfma16(a, bt0, accp[ms][0]);
      accp[ms][1] = mfma16(a, bt1, accp[ms][1]);
      accq[ms][0] = mfma16(a, bb0, accq[ms][0]);
      accq[ms][1] = mfma16(a, bb1, accq[ms][1]);
    }
  }

#pragma unroll
  for (int ms = 0; ms < 4; ++ms)
#pragma unroll
    for (int j = 0; j < 2; ++j) {
      const int n = wv * 32 + j * 16 + l16;
#pragma unroll
      for (int r = 0; r < 4; ++r)
        t1[(ms * 16 + quad * 4 + r) * EPAD + n] = (bf16_t)(accp[ms][j][r] + b1v[j]);
    }
  __syncthreads();
  {
    const int row = tid >> 2, cc = (tid & 3) * 32;
    const int node = tb + row;
    if (node < kN) {
#pragma unroll
      for (int u = 0; u < 4; ++u)
        *(bf16x8*)(P + (size_t)node * kD + cc + u * 8) = *(const bf16x8*)&t1[row * EPAD + cc + u * 8];
    }
  }
  __syncthreads();
#pragma unroll
  for (int ms = 0; ms < 4; ++ms)
#pragma unroll
    for (int j = 0; j < 2; ++j) {
      const int n = wv * 32 + j * 16 + l16;
#pragma unroll
      for (int r = 0; r < 4; ++r)
        t1[(ms * 16 + quad * 4 + r) * EPAD + n] = (bf16_t)accq[ms][j][r];
    }
  __syncthreads();
  {
    const int row = tid >> 2, cc = (tid & 3) * 32;
    const int node = tb + row;
    if (node < kN) {
#pragma unroll
      for (int u = 0; u < 4; ++u)
        *(bf16x8*)(Q + (size_t)node * kD + cc + u * 8) = *(const bf16x8*)&t1[row * EPAD + cc + u * 8];
    }
  }
}

// ---------------- K3: fused: sort -> edge MLP (Q via 3-buffer LDS-DMA, 2-tile-deep) -> LDS agg -> node MLP ----------------
// Block b owns nodes [b*32, b*32+32) and slot bucket b. Each wave consumes only the Q bytes
// it DMA'd itself -> no barrier in the edge loop; overlap via vmcnt(8) with 12 in flight.
__global__ __launch_bounds__(256, 2) void fused_kernel(
    const bf16_t* __restrict__ P, const bf16_t* __restrict__ Q,
    const int* __restrict__ slot_lc, const int* __restrict__ cursor,
    const bf16_t* __restrict__ W2T, const float* __restrict__ eb2,
    const bf16_t* __restrict__ h_bf, const float* __restrict__ h,
    const bf16_t* __restrict__ nW1T, const bf16_t* __restrict__ nW2T,
    const float* __restrict__ nb1, const float* __restrict__ nb2,
    float* __restrict__ out) {
  __shared__ float aggbuf[BKT * ASTR];    // 16896 B; aliased by t1 in node phase
  __shared__ int  sorted[kCap];           // 4096 B
  __shared__ int  s_bin[BKT];             // 128 B
  __shared__ bf16_t P_lds[BKT * EPAD];    // 8704 B
  __shared__ bf16_t qbuf[3 * 64 * kD];    // 49152 B: 3 bufs x 64 edges x 256 B

  const int tid  = threadIdx.x;
  const int wv   = tid >> 6;              // 0..3
  const int lane = tid & 63;
  const int l16  = lane & 15;
  const int quad = lane >> 4;
  const int g0   = blockIdx.x * BKT;

  for (int i = tid; i < BKT * ASTR; i += 256) aggbuf[i] = 0.0f;
  if (tid < BKT) s_bin[tid] = 0;
  // stage this block's 32 P rows (read once)
  for (int i = tid; i < BKT * 16; i += 256) {
    const int row = i >> 4, fo = (i & 15) * 8;
    const int gr = min(g0 + row, kN - 1);
    *(bf16x8*)&P_lds[row * EPAD + fo] = *(const bf16x8*)(P + (size_t)gr * kD + fo);
  }
  const int cnt = min(cursor[blockIdx.x * 16], kCap);
  const int sbase = blockIdx.x * kCap;
  __syncthreads();

  // ---- counting sort by lrow ----
  for (int i = tid; i < cnt; i += 256) atomicAdd(&s_bin[slot_lc[sbase + i] >> 16], 1);
  __syncthreads();
  if (tid == 0) {
    int run = 0;
#pragma unroll
    for (int r = 0; r < BKT; ++r) {
      const int c = s_bin[r];
      s_bin[r] = run;
      run += c;
    }
  }
  __syncthreads();
  for (int i = tid; i < cnt; i += 256) {
    const int w = slot_lc[sbase + i];
    sorted[atomicAdd(&s_bin[w >> 16], 1)] = w;
  }
  __syncthreads();

  float b2v[8];
#pragma unroll
  for (int j = 0; j < 8; ++j) b2v[j] = eb2[j * 16 + l16];

  // ---- edge phase: 64-edge tiles (16/wave), Q triple-buffered via global_load_lds ----
  // DMA lane map: lane l -> edge e=l&15, chunk q=l>>4; instr i covers byte chunk (i*4+q)*16
  // of Q row. LDS layout: buf*16384 + wv*4096 + i*1024 + l*16  => [ks=i][quad=q][e]*16B.
  const int ntiles = (cnt + 63) >> 6;
  char* qb_bytes = (char*)qbuf;

  auto dma_tile = [&](int bufofs, int col) {
    const char* gp = (const char*)(Q + (size_t)col * kD) + quad * 16;
    char* lb = qb_bytes + bufofs + wv * 4096;
#pragma unroll
    for (int i = 0; i < 4; ++i) {
      __builtin_amdgcn_global_load_lds(
          (const __attribute__((address_space(1))) void*)(gp + i * 64),
          (__attribute__((address_space(3))) void*)(lb + i * 1024),
          16, 0, 0);
    }
  };

  // prologue: prefetch tiles 0 and 1 (always issue; dummy col 0 when invalid)
  int w_cur, w_nxt;
  {
    const int idx0 = wv * 16 + l16;
    const int idx1 = 64 + wv * 16 + l16;
    w_cur = (idx0 < cnt) ? sorted[idx0] : -1;
    w_nxt = (idx1 < cnt) ? sorted[idx1] : -1;
    dma_tile(0, (w_cur >= 0) ? (w_cur & 0xFFFF) : 0);
    dma_tile(16384, (w_nxt >= 0) ? (w_nxt & 0xFFFF) : 0);
  }

  int bc = 0, bn = 16384, bn2 = 32768;  // rotating buffer byte offsets
  for (int t = 0; t < ntiles; ++t) {
    const int idx2 = (t + 2) * 64 + wv * 16 + l16;
    const int w_nx2 = (idx2 < cnt) ? sorted[idx2] : -1;
    dma_tile(bn2, (w_nx2 >= 0) ? (w_nx2 & 0xFFFF) : 0);  // always issue: uniform vmcnt math
    __builtin_amdgcn_s_waitcnt(0x0F78);   // vmcnt(8): tile t's 4 DMAs done; t+1,t+2 in flight
    __builtin_amdgcn_sched_barrier(0);    // keep ds_reads below the wait

    const int lr = (w_cur >= 0) ? (w_cur >> 16) : -1;
    const int lrow = (lr >= 0) ? lr : 0;
    const bf16_t* qb = qbuf + (size_t)(bc / 2 + wv * 2048 + quad * 128 + l16 * 8);

    bf16x8 af[4];
#pragma unroll
    for (int ks = 0; ks < 4; ++ks) {
      const bf16x8 p = *(const bf16x8*)&P_lds[lrow * EPAD + ks * 32 + quad * 8];
      const bf16x8 q = *(const bf16x8*)(qb + ks * 512);
      bf16x8 a;
#pragma unroll
      for (int u = 0; u < 8; ++u) a[u] = (bf16_t)silu_f((float)p[u] + (float)q[u]);
      af[ks] = a;
    }

    f32x4 acc[8];
#pragma unroll
    for (int j = 0; j < 8; ++j) acc[j] = (f32x4){0.f, 0.f, 0.f, 0.f};
#pragma unroll
    for (int ks = 0; ks < 4; ++ks)
#pragma unroll
      for (int j = 0; j < 8; ++j) {
        const bf16x8 b = *(const bf16x8*)(W2T + (size_t)(j * 16 + l16) * kD + ks * 32 + quad * 8);
        acc[j] = mfma16(af[ks], b, acc[j]);
      }

    // epilogue: silu + run-merged LDS atomic scatter (rows grouped by sort)
    int rows[4];
#pragma unroll
    for (int r = 0; r < 4; ++r) rows[r] = __shfl(lr, quad * 4 + r, 64);
#pragma unroll
    for (int j = 0; j < 8; ++j) {
      const int cbase = j * 16 + l16;
      float run = silu_f(acc[j][0] + b2v[j]);
      int cur = rows[0];
#pragma unroll
      for (int r = 1; r < 4; ++r) {
        const float v = silu_f(acc[j][r] + b2v[j]);
        if (rows[r] == cur) {
          run += v;
        } else {
          if (cur >= 0) atomicAdd(&aggbuf[cur * ASTR + cbase], run);
          cur = rows[r];
          run = v;
        }
      }
      if (cur >= 0) atomicAdd(&aggbuf[cur * ASTR + cbase], run);
    }

    w_cur = w_nxt;
    w_nxt = w_nx2;
    const int tmp = bc; bc = bn; bn = bn2; bn2 = tmp;
  }
  __syncthreads();

  // ---- node phase: out = h + silu([h | agg] @ nW1 + nb1) @ nW2 + nb2 ----
  const int n0 = wv * 32 + l16;
  const int n1 = n0 + 16;
  const float b1v[2] = {nb1[n0], nb1[n1]};
  const float b2n[2] = {nb2[n0], nb2[n1]};

  f32x4 acc[2][2];
#pragma unroll
  for (int ms = 0; ms < 2; ++ms)
#pragma unroll
    for (int j = 0; j < 2; ++j) acc[ms][j] = (f32x4){0.f, 0.f, 0.f, 0.f};

#pragma unroll
  for (int ks = 0; ks < 8; ++ks) {
    const bf16_t* wp = nW1T + ks * 32 + quad * 8;
    const bf16x8 b0 = *(const bf16x8*)(wp + (size_t)n0 * 256);
    const bf16x8 bq = *(const bf16x8*)(wp + (size_t)n1 * 256);
#pragma unroll
    for (int ms = 0; ms < 2; ++ms) {
      bf16x8 a;
      if (ks < 4) {
        int node = g0 + ms * 16 + l16;
        node = node < kN ? node : kN - 1;
        a = *(const bf16x8*)(h_bf + (size_t)node * kD + ks * 32 + quad * 8);
      } else {
        const int lrow = ms * 16 + l16;
        const float* ap = &aggbuf[lrow * ASTR + (ks - 4) * 32 + quad * 8];
        const float4 f0 = *(const float4*)ap;
        const float4 f1 = *(const float4*)(ap + 4);
        a = (bf16x8){(bf16_t)f0.x, (bf16_t)f0.y, (bf16_t)f0.z, (bf16_t)f0.w,
                     (bf16_t)f1.x, (bf16_t)f1.y, (bf16_t)f1.z, (bf16_t)f1.w};
      }
      acc[ms][0] = mfma16(a, b0, acc[ms][0]);
      acc[ms][1] = mfma16(a, bq, acc[ms][1]);
    }
  }
  __syncthreads();  // aggbuf reads done -> alias t1

  bf16_t* t1 = (bf16_t*)aggbuf;
#pragma unroll
  for (int ms = 0; ms < 2; ++ms)
#pragma unroll
    for (int j = 0; j < 2; ++j) {
      const int n = wv * 32 + j * 16 + l16;
#pragma unroll
      for (int r = 0; r < 4; ++r) {
        const int m = ms * 16 + quad * 4 + r;
        t1[m * EPAD + n] = (bf16_t)silu_f(acc[ms][j][r] + b1v[j]);
      }
    }
  __syncthreads();

  f32x4 acc2[2][2];
#pragma unroll
  for (int ms = 0; ms < 2; ++ms)
#pragma unroll
    for (int j = 0; j < 2; ++j) acc2[ms][j] = (f32x4){0.f, 0.f, 0.f, 0.f};
#pragma unroll
  for (int ks = 0; ks < 4; ++ks) {
    const bf16_t* wp = nW2T + ks * 32 + quad * 8;
    const bf16x8 b0 = *(const bf16x8*)(wp + (size_t)n0 * 128);
    const bf16x8 bq = *(const bf16x8*)(wp + (size_t)n1 * 128);
#pragma unroll
    for (int ms = 0; ms < 2; ++ms) {
      const bf16x8 a = *(const bf16x8*)&t1[(ms * 16 + l16) * EPAD + ks * 32 + quad * 8];
      acc2[ms][0] = mfma16(a, b0, acc2[ms][0]);
      acc2[ms][1] = mfma16(a, bq, acc2[ms][1]);
    }
  }

#pragma unroll
  for (int ms = 0; ms < 2; ++ms)
#pragma unroll
    for (int j = 0; j < 2; ++j) {
      const int n = wv * 32 + j * 16 + l16;
#pragma unroll
      for (int r = 0; r < 4; ++r) {
        const int node = g0 + ms * 16 + quad * 4 + r;
        if (node < kN) {
          const size_t o = (size_t)node * kD + n;
          out[o] = h[o] + acc2[ms][j][r] + b2n[j];
        }
      }
    }
}

// ---------------- launch ----------------
extern "C" void kernel_launch(void* const* d_in, const int* in_sizes, int n_in,
                              void* d_out, int out_size, void* d_ws, size_t ws_size,
                              hipStream_t stream) {
  const float* h   = (const float*)d_in[0];
  const int*   ei  = (const int*)d_in[1];
  const float* eW1 = (const float*)d_in[2];
  const float* eb1 = (const float*)d_in[3];
  const float* eW2 = (const float*)d_in[4];
  const float* eb2 = (const float*)d_in[5];
  const float* nW1 = (const float*)d_in[6];
  const float* nb1 = (const float*)d_in[7];
  const float* nW2 = (const float*)d_in[8];
  const float* nb2 = (const float*)d_in[9];
  float* out = (float*)d_out;

  char* ws = (char*)d_ws;
  size_t off = 0;
  auto alloc = [&](size_t bytes) {
    void* p = ws + off;
    off += (bytes + 255) & ~(size_t)255;
    return p;
  };
  bf16_t* h_bf    = (bf16_t*)alloc((size_t)kN * kD * 2);   // 12.8 MB
  bf16_t* W1T     = (bf16_t*)alloc(256 * 128 * 2);
  bf16_t* W2T     = (bf16_t*)alloc(128 * 128 * 2);
  bf16_t* nW1T    = (bf16_t*)alloc(256 * 128 * 2);
  bf16_t* nW2T    = (bf16_t*)alloc(128 * 128 * 2);
  bf16_t* P       = (bf16_t*)alloc((size_t)kN * kD * 2);   // 12.8 MB
  bf16_t* Q       = (bf16_t*)alloc((size_t)kN * kD * 2);   // 12.8 MB
  int*    cursor  = (int*)alloc((size_t)NBKT * 16 * 4);    // 100 KB, 64 B padded
  int*    slot_lc = (int*)alloc((size_t)NBKT * kCap * 4);  // 6.4 MB

  prep_kernel<<<128, 256, 0, stream>>>(eW1, eW2, nW1, nW2, W1T, W2T, nW1T, nW2T, cursor);
  mega_kernel<<<BUCKET_BLOCKS + PQT, 256, 0, stream>>>(h, ei, W1T, eb1,
                                                       h_bf, P, Q, cursor, slot_lc);
  fused_kernel<<<NBKT, 256, 0, stream>>>(P, Q, slot_lc, cursor, W2T, eb2,
                                         h_bf, h, nW1T, nW2T, nb1, nb2, out);
}